// Round 10
// baseline (521.994 us; speedup 1.0000x reference)
//
#include <hip/hip_runtime.h>

// ES gradient for 2-layer MLP (D_IN=1024, HID=2048, D_OUT=10, POP=40, STD=0.1).
// k_xsplit (x -> fragment-order f16 RTN) -> k_base (fp32) ->
// k_big (2-product split MFMA: E=hi+lo f16, x=f16; E-only swizzled LDS;
// B-frags direct from global, coalesced 1KB/wave) -> k_loss -> k_rank -> k_grad.
// Losses matter only through RANKS; E-split + x-f16 T-err ~8e-3 abs (T~32),
// loss err ~1e-3 << rank gaps. Tripwire: absmax must stay 2.441e-4 exactly.
// Register discipline (measured R5-R9): hipcc caps VGPR at 256/min_waves_arg;
// (256,2)=128 cap. Live state here ~115 => no spill at 4 waves/SIMD.

#define NPLL 2119690LL          // N_PARAMS
#define S1_  2097152            // W1 end
#define S2_  2099200            // b1 end
#define S3_  2119680            // W2 end

// ws layout (f32 units):
//   base : [0, 524288)            base[j][b]  f32
//   ppu  : [524288, 3801088)      f16-packed [40][2][32 jt][256 b][5 dw]
//   loss : [3801088, 3801168)
//   g    : [3801168, 3801208)
//   xf   : [3801216, +131072)     f16 frag-order [32 kt][16 bblk][4 qh][16 lm][8]
#define WS_PP   524288
#define WS_LOSS 3801088
#define WS_G    3801168
#define WS_XF   3801216

typedef _Float16 f16;
typedef __fp16   fp16x2 __attribute__((ext_vector_type(2)));
typedef _Float16 f16x2t __attribute__((ext_vector_type(2)));
typedef _Float16 f16x8 __attribute__((ext_vector_type(8)));
typedef float    f32x4 __attribute__((ext_vector_type(4)));

__device__ __forceinline__ unsigned pk2r(float a, float b, float& ra, float& rb) {
  fp16x2 h = __builtin_amdgcn_cvt_pkrtz(a, b);   // v_cvt_pkrtz_f16_f32 (RTZ)
  ra = a - (float)h[0];
  rb = b - (float)h[1];
  return __builtin_bit_cast(unsigned, h);
}
__device__ __forceinline__ unsigned pk2(float a, float b) {
  fp16x2 h = __builtin_amdgcn_cvt_pkrtz(a, b);
  return __builtin_bit_cast(unsigned, h);
}
__device__ __forceinline__ unsigned packh(float a, float b) {  // RTN pack
  f16x2t v = {(f16)a, (f16)b};
  return __builtin_bit_cast(unsigned, v);
}
__device__ __forceinline__ float unpk_lo(unsigned u) {
  return (float)__builtin_bit_cast(f16, (unsigned short)(u & 0xffffu));
}
__device__ __forceinline__ float unpk_hi(unsigned u) {
  return (float)__builtin_bit_cast(f16, (unsigned short)(u >> 16));
}

// ---------------- k_xsplit: x -> fragment-order f16 (RTN) -------------------
// Element (kt,bblk,qh,lm,e) = x[b=bblk*16+lm][k=kt*32+qh*8+e].
// A wave's B-frag load (fixed kt,bblk; lanes (qh,lm)) is 1 KB contiguous.
__global__ __launch_bounds__(256) void k_xsplit(const float* __restrict__ x,
                                                f16* __restrict__ xf) {
  const int idx = blockIdx.x * 256 + threadIdx.x;  // 32768
  const int b  = idx >> 7;           // 0..255
  const int k8 = idx & 127;          // k-octet index
  const int kt = k8 >> 2, qh = k8 & 3;
  const int bblk = b >> 4, lm = b & 15;
  float4 a0 = *(const float4*)&x[(size_t)b * 1024 + k8 * 8];
  float4 a1 = *(const float4*)&x[(size_t)b * 1024 + k8 * 8 + 4];
  uint4 H;
  H.x = packh(a0.x, a0.y);
  H.y = packh(a0.z, a0.w);
  H.z = packh(a1.x, a1.y);
  H.w = packh(a1.z, a1.w);
  f16* dst = &xf[(((size_t)(kt * 16 + bblk) * 4 + qh) * 16 + lm) * 8];
  *(uint4*)dst = H;
}

// ---------------- k_base: base[j][b] = (x @ W1)[b][j] + b1[j] (fp32) --------
__global__ __launch_bounds__(256) void k_base(const float* __restrict__ x,
                                              const float* __restrict__ W1,
                                              const float* __restrict__ b1,
                                              float* __restrict__ base) {
  constexpr int STR = 72;
  __shared__ float xsm[32 * STR];
  __shared__ float es[32 * STR];
  const int t  = threadIdx.x;
  const int j0 = blockIdx.x * 64;
  const int b0 = blockIdx.y * 32;
  const int tj = t & 15;
  const int tb = t >> 4;
  float acc[4][2] = {};
  for (int k0 = 0; k0 < 1024; k0 += 32) {
    __syncthreads();
    {
      int bb = t >> 3, kq = t & 7;
      float4 v = *(const float4*)&x[(size_t)(b0 + bb) * 1024 + k0 + kq * 4];
      int kb = kq * 4;
      xsm[(kb + 0) * STR + bb] = v.x;
      xsm[(kb + 1) * STR + bb] = v.y;
      xsm[(kb + 2) * STR + bb] = v.z;
      xsm[(kb + 3) * STR + bb] = v.w;
    }
#pragma unroll
    for (int r = 0; r < 2; ++r) {
      int idx = t + r * 256;
      int k = idx >> 4, jq = idx & 15, col = jq * 4;
      float4 v = *(const float4*)&W1[(size_t)(k0 + k) * 2048 + j0 + col];
      *(float4*)&es[k * STR + col + 4 * (col >> 5)] = v;
    }
    __syncthreads();
#pragma unroll 8
    for (int k = 0; k < 32; ++k) {
      const int ce = tj * 4;
      float4 e = *(const float4*)&es[k * STR + ce + 4 * (ce >> 5)];
      float2 a = *(const float2*)&xsm[k * STR + tb * 2];
      acc[0][0] += e.x * a.x; acc[0][1] += e.x * a.y;
      acc[1][0] += e.y * a.x; acc[1][1] += e.y * a.y;
      acc[2][0] += e.z * a.x; acc[2][1] += e.z * a.y;
      acc[3][0] += e.w * a.x; acc[3][1] += e.w * a.y;
    }
  }
#pragma unroll
  for (int jj = 0; jj < 4; ++jj) {
    int j = j0 + tj * 4 + jj;
    float bv = b1[j];
    float2 o = make_float2(acc[jj][0] + bv, acc[jj][1] + bv);
    *(float2*)&base[(size_t)j * 256 + b0 + tb * 2] = o;
  }
}

// ---------------- k_big: 2-product split MFMA x@E1 + fused epilogue ---------
// grid (32 jt, 40 p), 256 threads = 4 waves; block tile j64 x b256; each wave
// owns a 64-wide b-slice and all 64 j rows. E-only LDS (8 KB, XOR-swizzled).
__global__ __launch_bounds__(256, 2) void k_big(const f16* __restrict__ xf,
                                                const float* __restrict__ noise,
                                                const float* __restrict__ W2,
                                                const float* __restrict__ base,
                                                unsigned* __restrict__ ppu) {
  __shared__ __align__(16) char smem[8192];
  f16* eA = (f16*)smem;            // [64 j][8 chunks of 8, XOR-swizzled]
  float* w2l = (float*)smem;       // epilogue overlay (5.4 KB <= 8 KB)
  float* e2l = w2l + 640;
  float* e1l = e2l + 640;

  const int t    = threadIdx.x;
  const int jt   = blockIdx.x, p = blockIdx.y;
  const int j0   = jt * 64;
  const int wave = t >> 6, lane = t & 63;
  const int lm   = lane & 15, qh = lane >> 4;   // frag row / k-octet
  const int g4   = qh * 4;
  const int bw   = wave * 64;
  const size_t pN = (size_t)p * NPLL;
  const int srow = t & 63, sq = t >> 6;         // staging role
  const int sswz = (srow & 7) << 3;

  float ve[8];
  f32x4 acc[4][4];
#pragma unroll
  for (int a = 0; a < 4; ++a)
#pragma unroll
    for (int b = 0; b < 4; ++b) acc[a][b] = (f32x4){0.f, 0.f, 0.f, 0.f};

  const float* Ebase = noise + pN + (size_t)(sq * 8) * 2048 + j0 + srow;
  const int aswz = (lm & 7) << 3;

  // prologue: E loads for ks=0
#pragma unroll
  for (int d = 0; d < 8; ++d) ve[d] = Ebase[(size_t)d * 2048];

  for (int ks = 0; ks < 32; ++ks) {
    __syncthreads();   // previous MFMA reads done; eA free
    {  // stage E: convert 8 f32 -> hi/lo 16B, swizzled write
      float r0, r1, r2, r3, r4, r5, r6, r7;
      uint4 H, L;
      H.x = pk2r(ve[0], ve[1], r0, r1);
      H.y = pk2r(ve[2], ve[3], r2, r3);
      H.z = pk2r(ve[4], ve[5], r4, r5);
      H.w = pk2r(ve[6], ve[7], r6, r7);
      *(uint4*)&eA[srow * 64 + ((sq * 8) ^ sswz)] = H;
      L.x = pk2(r0, r1); L.y = pk2(r2, r3);
      L.z = pk2(r4, r5); L.w = pk2(r6, r7);
      *(uint4*)&eA[srow * 64 + (((sq + 4) * 8) ^ sswz)] = L;
    }
    // B fragments for THIS step (f16 single): 1 KB contiguous per (wave,nf)
    const f16* xk = xf + (size_t)ks * 8192;
    f16x8 B[4];
#pragma unroll
    for (int nf = 0; nf < 4; ++nf)
      B[nf] = *(const f16x8*)&xk[(wave * 4 + nf) * 512 + qh * 128 + lm * 8];
    // prefetch next-step E into regs (completes during MFMA phase)
    if (ks < 31) {
      const float* En = Ebase + (size_t)(ks + 1) * 32 * 2048;
#pragma unroll
      for (int d = 0; d < 8; ++d) ve[d] = En[(size_t)d * 2048];
    }
    __syncthreads();   // eA tile ready
#pragma unroll
    for (int mf = 0; mf < 4; ++mf) {
      const int ra = mf * 16 + lm;
      f16x8 Ah = *(const f16x8*)&eA[ra * 64 + ((qh * 8) ^ aswz)];
      f16x8 Al = *(const f16x8*)&eA[ra * 64 + (((qh + 4) * 8) ^ aswz)];
#pragma unroll
      for (int nf = 0; nf < 4; ++nf) {
        acc[mf][nf] = __builtin_amdgcn_mfma_f32_16x16x32_f16(Ah, B[nf], acc[mf][nf], 0, 0, 0);
        acc[mf][nf] = __builtin_amdgcn_mfma_f32_16x16x32_f16(Al, B[nf], acc[mf][nf], 0, 0, 0);
      }
    }
  }

  // ---- epilogue: tables overlay dead eA region ----
  __syncthreads();
  for (int i = t; i < 640; i += 256) {
    w2l[i] = W2[j0 * 10 + i];
    e2l[i] = noise[pN + S2_ + (size_t)j0 * 10 + i];
  }
  if (t < 64) e1l[t] = noise[pN + S1_ + j0 + t];
  __syncthreads();

#pragma unroll 1
  for (int s = 0; s < 2; ++s) {
    const float sf = s ? -0.1f : 0.1f;
    float ppv[4][10];
#pragma unroll
    for (int nf = 0; nf < 4; ++nf)
#pragma unroll
      for (int o = 0; o < 10; ++o) ppv[nf][o] = 0.f;
#pragma unroll
    for (int mf = 0; mf < 4; ++mf)
#pragma unroll
      for (int r = 0; r < 4; ++r) {
        const int jl = mf * 16 + g4 + r;       // D row = (lane>>4)*4 + reg
        const float e1v = e1l[jl];
        float w2s[10];
#pragma unroll
        for (int o = 0; o < 10; ++o)
          w2s[o] = fmaf(sf, e2l[jl * 10 + o], w2l[jl * 10 + o]);
#pragma unroll
        for (int nf = 0; nf < 4; ++nf) {
          const float bs = base[(size_t)(j0 + jl) * 256 + bw + nf * 16 + lm];
          const float h = fmaxf(fmaf(sf, acc[mf][nf][r] + e1v, bs), 0.f);
#pragma unroll
          for (int o = 0; o < 10; ++o) ppv[nf][o] = fmaf(h, w2s[o], ppv[nf][o]);
        }
      }
    // sum the 4 row-groups (lane bits 4,5); wave covers all 64 j
#pragma unroll
    for (int nf = 0; nf < 4; ++nf)
#pragma unroll
      for (int o = 0; o < 10; ++o) {
        float v = ppv[nf][o];
        v += __shfl_xor(v, 16, 64);
        v += __shfl_xor(v, 32, 64);
        ppv[nf][o] = v;
      }
    if (lane < 16) {
#pragma unroll
      for (int nf = 0; nf < 4; ++nf) {
        const int bl = bw + nf * 16 + lm;
        const size_t u0 = ((((size_t)p * 2 + s) * 32 + jt) * 256 + bl) * 5;
        ppu[u0 + 0] = packh(ppv[nf][0], ppv[nf][1]);
        ppu[u0 + 1] = packh(ppv[nf][2], ppv[nf][3]);
        ppu[u0 + 2] = packh(ppv[nf][4], ppv[nf][5]);
        ppu[u0 + 3] = packh(ppv[nf][6], ppv[nf][7]);
        ppu[u0 + 4] = packh(ppv[nf][8], ppv[nf][9]);
      }
    }
  }
}

// ---------------- k_loss: 80 losses ----------------
__global__ __launch_bounds__(256) void k_loss(const unsigned* __restrict__ ppu,
                                              const float* __restrict__ y,
                                              const float* __restrict__ b2,
                                              const float* __restrict__ noise,
                                              float* __restrict__ loss) {
  const int b = threadIdx.x;
  const int p = blockIdx.x >> 1, s = blockIdx.x & 1;
  const float sf = s ? -0.1f : 0.1f;
  const size_t pN = (size_t)p * NPLL;
  float pred[10];
#pragma unroll
  for (int o = 0; o < 10; ++o) pred[o] = b2[o] + sf * noise[pN + S3_ + o];
  for (int jt = 0; jt < 32; ++jt) {
    const size_t u0 = ((((size_t)p * 2 + s) * 32 + jt) * 256 + b) * 5;
#pragma unroll
    for (int q = 0; q < 5; ++q) {
      unsigned u = ppu[u0 + q];
      pred[2 * q]     += unpk_lo(u);
      pred[2 * q + 1] += unpk_hi(u);
    }
  }
  float e = 0.f;
#pragma unroll
  for (int o = 0; o < 10; ++o) {
    float d = pred[o] - y[b * 10 + o];
    e += d * d;
  }
  __shared__ float red[256];
  red[b] = e;
  __syncthreads();
  for (int st = 128; st > 0; st >>= 1) {
    if (b < st) red[b] += red[b + st];
    __syncthreads();
  }
  if (b == 0) loss[blockIdx.x] = red[0] * (1.0f / 2560.0f);
}

// ---------------- k_rank: stable centered ranks -> pair coefficients --------
__global__ void k_rank(const float* __restrict__ loss, float* __restrict__ g) {
  __shared__ float ls[80];
  __shared__ float rk[80];
  const int t = threadIdx.x;
  if (t < 80) ls[t] = loss[t];
  __syncthreads();
  if (t < 80) {
    float li = ls[t];
    int r = 0;
    for (int j = 0; j < 80; ++j) {
      float lj = ls[j];
      r += (lj < li) || (lj == li && j < t);  // stable tie-break = argsort
    }
    rk[t] = (float)r;
  }
  __syncthreads();
  if (t < 40) g[t] = (rk[2 * t] - rk[2 * t + 1]) * (1.0f / (79.0f * 40.0f));
}

// ---------------- k_grad: out[k] = sum_p noise[p][k] * g[p] -----------------
__global__ __launch_bounds__(256) void k_grad(const float* __restrict__ noise,
                                              const float* __restrict__ g,
                                              float* __restrict__ out) {
  __shared__ float gg[40];
  const int t = threadIdx.x;
  if (t < 40) gg[t] = g[t];
  __syncthreads();
  const long long NH = NPLL / 2;
  long long idx = (long long)blockIdx.x * 256 + t;
  if (idx >= NH) return;
  float2 a = make_float2(0.f, 0.f);
#pragma unroll 8
  for (int p = 0; p < 40; ++p) {
    float2 v = *(const float2*)&noise[(size_t)p * NPLL + idx * 2];
    a.x += v.x * gg[p];
    a.y += v.y * gg[p];
  }
  *(float2*)&out[idx * 2] = a;
}

extern "C" void kernel_launch(void* const* d_in, const int* in_sizes, int n_in,
                              void* d_out, int out_size, void* d_ws, size_t ws_size,
                              hipStream_t stream) {
  const float* x     = (const float*)d_in[0];
  const float* y     = (const float*)d_in[1];
  const float* W1    = (const float*)d_in[2];
  const float* b1    = (const float*)d_in[3];
  const float* W2    = (const float*)d_in[4];
  const float* b2    = (const float*)d_in[5];
  const float* noise = (const float*)d_in[6];
  float* out  = (float*)d_out;
  float* ws   = (float*)d_ws;   // ~15.7 MB used
  float* base = ws;
  unsigned* ppu = (unsigned*)(ws + WS_PP);
  float* loss = ws + WS_LOSS;
  float* g    = ws + WS_G;
  f16* xf = (f16*)(ws + WS_XF);

  k_xsplit<<<128, 256, 0, stream>>>(x, xf);
  k_base<<<dim3(32, 8), 256, 0, stream>>>(x, W1, b1, base);
  k_big<<<dim3(32, 40), 256, 0, stream>>>(xf, noise, W2, base, ppu);
  k_loss<<<80, 256, 0, stream>>>(ppu, y, b2, noise, loss);
  k_rank<<<1, 128, 0, stream>>>(loss, g);
  k_grad<<<4141, 256, 0, stream>>>(noise, g, out);
}

// Round 11
// 413.643 us; speedup vs baseline: 1.2619x; 1.2619x over previous
//
#include <hip/hip_runtime.h>

// ES gradient for 2-layer MLP (D_IN=1024, HID=2048, D_OUT=10, POP=40, STD=0.1).
// k_xsplit (x -> fragment-order f16 RTN) -> k_base (fp32) ->
// k_big (2-product split MFMA: E=hi+lo f16 x@E1; double-buffered E LDS,
// SINGLE barrier/step, loads issued post-barrier so HBM latency overlaps MFMA)
// -> k_loss -> k_rank -> k_grad.
// Rank-exactness verified on HW (R10): absmax 2.441e-4 with 2-product split.
// Register discipline (R5-R10 measured): any __launch_bounds__ min-occupancy
// arg caps VGPR (128 at (256,2)) and this kernel's ~150 live regs then spill
// deterministically (374 MB HBM writes). Leave uncapped: 256 VGPR, no spill.

#define NPLL 2119690LL          // N_PARAMS
#define S1_  2097152            // W1 end
#define S2_  2099200            // b1 end
#define S3_  2119680            // W2 end

// ws layout (f32 units):
//   base : [0, 524288)            base[j][b]  f32
//   ppu  : [524288, 3801088)      f16-packed [40][2][32 jt][256 b][5 dw]
//   loss : [3801088, 3801168)
//   g    : [3801168, 3801208)
//   xf   : [3801216, +131072)     f16 frag-order [32 kt][16 bblk][4 qh][16 lm][8]
#define WS_PP   524288
#define WS_LOSS 3801088
#define WS_G    3801168
#define WS_XF   3801216

typedef _Float16 f16;
typedef __fp16   fp16x2 __attribute__((ext_vector_type(2)));
typedef _Float16 f16x2t __attribute__((ext_vector_type(2)));
typedef _Float16 f16x8 __attribute__((ext_vector_type(8)));
typedef float    f32x4 __attribute__((ext_vector_type(4)));

__device__ __forceinline__ unsigned pk2r(float a, float b, float& ra, float& rb) {
  fp16x2 h = __builtin_amdgcn_cvt_pkrtz(a, b);   // v_cvt_pkrtz_f16_f32 (RTZ)
  ra = a - (float)h[0];
  rb = b - (float)h[1];
  return __builtin_bit_cast(unsigned, h);
}
__device__ __forceinline__ unsigned pk2(float a, float b) {
  fp16x2 h = __builtin_amdgcn_cvt_pkrtz(a, b);
  return __builtin_bit_cast(unsigned, h);
}
__device__ __forceinline__ unsigned packh(float a, float b) {  // RTN pack
  f16x2t v = {(f16)a, (f16)b};
  return __builtin_bit_cast(unsigned, v);
}
__device__ __forceinline__ float unpk_lo(unsigned u) {
  return (float)__builtin_bit_cast(f16, (unsigned short)(u & 0xffffu));
}
__device__ __forceinline__ float unpk_hi(unsigned u) {
  return (float)__builtin_bit_cast(f16, (unsigned short)(u >> 16));
}

// ---------------- k_xsplit: x -> fragment-order f16 (RTN) -------------------
// Element (kt,bblk,qh,lm,e) = x[b=bblk*16+lm][k=kt*32+qh*8+e].
// A wave's B-frag load (fixed kt,bblk; lanes (qh,lm)) is 1 KB contiguous.
__global__ __launch_bounds__(256) void k_xsplit(const float* __restrict__ x,
                                                f16* __restrict__ xf) {
  const int idx = blockIdx.x * 256 + threadIdx.x;  // 32768
  const int b  = idx >> 7;           // 0..255
  const int k8 = idx & 127;          // k-octet index
  const int kt = k8 >> 2, qh = k8 & 3;
  const int bblk = b >> 4, lm = b & 15;
  float4 a0 = *(const float4*)&x[(size_t)b * 1024 + k8 * 8];
  float4 a1 = *(const float4*)&x[(size_t)b * 1024 + k8 * 8 + 4];
  uint4 H;
  H.x = packh(a0.x, a0.y);
  H.y = packh(a0.z, a0.w);
  H.z = packh(a1.x, a1.y);
  H.w = packh(a1.z, a1.w);
  f16* dst = &xf[(((size_t)(kt * 16 + bblk) * 4 + qh) * 16 + lm) * 8];
  *(uint4*)dst = H;
}

// ---------------- k_base: base[j][b] = (x @ W1)[b][j] + b1[j] (fp32) --------
__global__ __launch_bounds__(256) void k_base(const float* __restrict__ x,
                                              const float* __restrict__ W1,
                                              const float* __restrict__ b1,
                                              float* __restrict__ base) {
  constexpr int STR = 72;
  __shared__ float xsm[32 * STR];
  __shared__ float es[32 * STR];
  const int t  = threadIdx.x;
  const int j0 = blockIdx.x * 64;
  const int b0 = blockIdx.y * 32;
  const int tj = t & 15;
  const int tb = t >> 4;
  float acc[4][2] = {};
  for (int k0 = 0; k0 < 1024; k0 += 32) {
    __syncthreads();
    {
      int bb = t >> 3, kq = t & 7;
      float4 v = *(const float4*)&x[(size_t)(b0 + bb) * 1024 + k0 + kq * 4];
      int kb = kq * 4;
      xsm[(kb + 0) * STR + bb] = v.x;
      xsm[(kb + 1) * STR + bb] = v.y;
      xsm[(kb + 2) * STR + bb] = v.z;
      xsm[(kb + 3) * STR + bb] = v.w;
    }
#pragma unroll
    for (int r = 0; r < 2; ++r) {
      int idx = t + r * 256;
      int k = idx >> 4, jq = idx & 15, col = jq * 4;
      float4 v = *(const float4*)&W1[(size_t)(k0 + k) * 2048 + j0 + col];
      *(float4*)&es[k * STR + col + 4 * (col >> 5)] = v;
    }
    __syncthreads();
#pragma unroll 8
    for (int k = 0; k < 32; ++k) {
      const int ce = tj * 4;
      float4 e = *(const float4*)&es[k * STR + ce + 4 * (ce >> 5)];
      float2 a = *(const float2*)&xsm[k * STR + tb * 2];
      acc[0][0] += e.x * a.x; acc[0][1] += e.x * a.y;
      acc[1][0] += e.y * a.x; acc[1][1] += e.y * a.y;
      acc[2][0] += e.z * a.x; acc[2][1] += e.z * a.y;
      acc[3][0] += e.w * a.x; acc[3][1] += e.w * a.y;
    }
  }
#pragma unroll
  for (int jj = 0; jj < 4; ++jj) {
    int j = j0 + tj * 4 + jj;
    float bv = b1[j];
    float2 o = make_float2(acc[jj][0] + bv, acc[jj][1] + bv);
    *(float2*)&base[(size_t)j * 256 + b0 + tb * 2] = o;
  }
}

// ---------------- k_big: 2-product split MFMA x@E1 + fused epilogue ---------
// grid (32 jt, 40 p), 256 threads = 4 waves; block tile j64 x b256; each wave
// owns a 64-wide b-slice and all 64 j rows. eA double-buffered (2 x 8 KB),
// ONE barrier per k-step; E/B prefetch for step ks+1 issued right AFTER the
// barrier of step ks so the HBM/L2 latency overlaps ds_read+MFMA+next cvt
// (the compiler's vmcnt(0) drain at a barrier otherwise kills the overlap).
__global__ __launch_bounds__(256) void k_big(const f16* __restrict__ xf,
                                             const float* __restrict__ noise,
                                             const float* __restrict__ W2,
                                             const float* __restrict__ base,
                                             unsigned* __restrict__ ppu) {
  __shared__ __align__(16) char smem[16384];   // eA[0] | eA[1]
  float* w2l = (float*)smem;       // epilogue overlay of buffer 0 (5.4 KB)
  float* e2l = w2l + 640;
  float* e1l = e2l + 640;

  const int t    = threadIdx.x;
  const int jt   = blockIdx.x, p = blockIdx.y;
  const int j0   = jt * 64;
  const int wave = t >> 6, lane = t & 63;
  const int lm   = lane & 15, qh = lane >> 4;   // frag row / k-octet
  const int g4   = qh * 4;
  const int bw   = wave * 64;
  const size_t pN = (size_t)p * NPLL;
  const int srow = t & 63, sq = t >> 6;         // staging role
  const int sswz = (srow & 7) << 3;
  const int aswz = (lm & 7) << 3;

  float ve[8];
  f16x8 Bc[4], Bn[4];
  f32x4 acc[4][4];
#pragma unroll
  for (int a = 0; a < 4; ++a)
#pragma unroll
    for (int b = 0; b < 4; ++b) acc[a][b] = (f32x4){0.f, 0.f, 0.f, 0.f};

  const float* Ebase = noise + pN + (size_t)(sq * 8) * 2048 + j0 + srow;
  const int boff = (wave * 4) * 512 + qh * 128 + lm * 8;

  // prologue: loads for ks = 0
#pragma unroll
  for (int d = 0; d < 8; ++d) ve[d] = Ebase[(size_t)d * 2048];
#pragma unroll
  for (int nf = 0; nf < 4; ++nf)
    Bc[nf] = *(const f16x8*)&xf[boff + nf * 512];

  for (int ks = 0; ks < 32; ++ks) {
    f16* eAc = (f16*)(smem + (ks & 1) * 8192);
    {  // stage E(ks): convert 8 f32 -> hi/lo 16B, swizzled write
      float r0, r1, r2, r3, r4, r5, r6, r7;
      uint4 H, L;
      H.x = pk2r(ve[0], ve[1], r0, r1);
      H.y = pk2r(ve[2], ve[3], r2, r3);
      H.z = pk2r(ve[4], ve[5], r4, r5);
      H.w = pk2r(ve[6], ve[7], r6, r7);
      *(uint4*)&eAc[srow * 64 + ((sq * 8) ^ sswz)] = H;
      L.x = pk2(r0, r1); L.y = pk2(r2, r3);
      L.z = pk2(r4, r5); L.w = pk2(r6, r7);
      *(uint4*)&eAc[srow * 64 + (((sq + 4) * 8) ^ sswz)] = L;
    }
    __syncthreads();   // eA[ks&1] visible; other buffer free for next write
    // issue next-step loads NOW: in flight across ds_read + MFMA + next cvt
    if (ks < 31) {
      const float* En = Ebase + (size_t)(ks + 1) * 32 * 2048;
#pragma unroll
      for (int d = 0; d < 8; ++d) ve[d] = En[(size_t)d * 2048];
      const f16* xn = xf + (size_t)(ks + 1) * 8192;
#pragma unroll
      for (int nf = 0; nf < 4; ++nf)
        Bn[nf] = *(const f16x8*)&xn[boff + nf * 512];
    }
#pragma unroll
    for (int mf = 0; mf < 4; ++mf) {
      const int ra = mf * 16 + lm;
      f16x8 Ah = *(const f16x8*)&eAc[ra * 64 + ((qh * 8) ^ aswz)];
      f16x8 Al = *(const f16x8*)&eAc[ra * 64 + (((qh + 4) * 8) ^ aswz)];
#pragma unroll
      for (int nf = 0; nf < 4; ++nf) {
        acc[mf][nf] = __builtin_amdgcn_mfma_f32_16x16x32_f16(Ah, Bc[nf], acc[mf][nf], 0, 0, 0);
        acc[mf][nf] = __builtin_amdgcn_mfma_f32_16x16x32_f16(Al, Bc[nf], acc[mf][nf], 0, 0, 0);
      }
    }
#pragma unroll
    for (int nf = 0; nf < 4; ++nf) Bc[nf] = Bn[nf];
  }

  // ---- epilogue: tables overlay dead eA buffer 0 ----
  __syncthreads();
  for (int i = t; i < 640; i += 256) {
    w2l[i] = W2[j0 * 10 + i];
    e2l[i] = noise[pN + S2_ + (size_t)j0 * 10 + i];
  }
  if (t < 64) e1l[t] = noise[pN + S1_ + j0 + t];
  __syncthreads();

#pragma unroll 1
  for (int s = 0; s < 2; ++s) {
    const float sf = s ? -0.1f : 0.1f;
    float ppv[4][10];
#pragma unroll
    for (int nf = 0; nf < 4; ++nf)
#pragma unroll
      for (int o = 0; o < 10; ++o) ppv[nf][o] = 0.f;
#pragma unroll
    for (int mf = 0; mf < 4; ++mf)
#pragma unroll
      for (int r = 0; r < 4; ++r) {
        const int jl = mf * 16 + g4 + r;       // D row = (lane>>4)*4 + reg
        const float e1v = e1l[jl];
        float w2s[10];
#pragma unroll
        for (int o = 0; o < 10; ++o)
          w2s[o] = fmaf(sf, e2l[jl * 10 + o], w2l[jl * 10 + o]);
#pragma unroll
        for (int nf = 0; nf < 4; ++nf) {
          const float bs = base[(size_t)(j0 + jl) * 256 + bw + nf * 16 + lm];
          const float h = fmaxf(fmaf(sf, acc[mf][nf][r] + e1v, bs), 0.f);
#pragma unroll
          for (int o = 0; o < 10; ++o) ppv[nf][o] = fmaf(h, w2s[o], ppv[nf][o]);
        }
      }
    // sum the 4 row-groups (lane bits 4,5); wave covers all 64 j
#pragma unroll
    for (int nf = 0; nf < 4; ++nf)
#pragma unroll
      for (int o = 0; o < 10; ++o) {
        float v = ppv[nf][o];
        v += __shfl_xor(v, 16, 64);
        v += __shfl_xor(v, 32, 64);
        ppv[nf][o] = v;
      }
    if (lane < 16) {
#pragma unroll
      for (int nf = 0; nf < 4; ++nf) {
        const int bl = bw + nf * 16 + lm;
        const size_t u0 = ((((size_t)p * 2 + s) * 32 + jt) * 256 + bl) * 5;
        ppu[u0 + 0] = packh(ppv[nf][0], ppv[nf][1]);
        ppu[u0 + 1] = packh(ppv[nf][2], ppv[nf][3]);
        ppu[u0 + 2] = packh(ppv[nf][4], ppv[nf][5]);
        ppu[u0 + 3] = packh(ppv[nf][6], ppv[nf][7]);
        ppu[u0 + 4] = packh(ppv[nf][8], ppv[nf][9]);
      }
    }
  }
}

// ---------------- k_loss: 80 losses ----------------
__global__ __launch_bounds__(256) void k_loss(const unsigned* __restrict__ ppu,
                                              const float* __restrict__ y,
                                              const float* __restrict__ b2,
                                              const float* __restrict__ noise,
                                              float* __restrict__ loss) {
  const int b = threadIdx.x;
  const int p = blockIdx.x >> 1, s = blockIdx.x & 1;
  const float sf = s ? -0.1f : 0.1f;
  const size_t pN = (size_t)p * NPLL;
  float pred[10];
#pragma unroll
  for (int o = 0; o < 10; ++o) pred[o] = b2[o] + sf * noise[pN + S3_ + o];
  for (int jt = 0; jt < 32; ++jt) {
    const size_t u0 = ((((size_t)p * 2 + s) * 32 + jt) * 256 + b) * 5;
#pragma unroll
    for (int q = 0; q < 5; ++q) {
      unsigned u = ppu[u0 + q];
      pred[2 * q]     += unpk_lo(u);
      pred[2 * q + 1] += unpk_hi(u);
    }
  }
  float e = 0.f;
#pragma unroll
  for (int o = 0; o < 10; ++o) {
    float d = pred[o] - y[b * 10 + o];
    e += d * d;
  }
  __shared__ float red[256];
  red[b] = e;
  __syncthreads();
  for (int st = 128; st > 0; st >>= 1) {
    if (b < st) red[b] += red[b + st];
    __syncthreads();
  }
  if (b == 0) loss[blockIdx.x] = red[0] * (1.0f / 2560.0f);
}

// ---------------- k_rank: stable centered ranks -> pair coefficients --------
__global__ void k_rank(const float* __restrict__ loss, float* __restrict__ g) {
  __shared__ float ls[80];
  __shared__ float rk[80];
  const int t = threadIdx.x;
  if (t < 80) ls[t] = loss[t];
  __syncthreads();
  if (t < 80) {
    float li = ls[t];
    int r = 0;
    for (int j = 0; j < 80; ++j) {
      float lj = ls[j];
      r += (lj < li) || (lj == li && j < t);  // stable tie-break = argsort
    }
    rk[t] = (float)r;
  }
  __syncthreads();
  if (t < 40) g[t] = (rk[2 * t] - rk[2 * t + 1]) * (1.0f / (79.0f * 40.0f));
}

// ---------------- k_grad: out[k] = sum_p noise[p][k] * g[p] -----------------
__global__ __launch_bounds__(256) void k_grad(const float* __restrict__ noise,
                                              const float* __restrict__ g,
                                              float* __restrict__ out) {
  __shared__ float gg[40];
  const int t = threadIdx.x;
  if (t < 40) gg[t] = g[t];
  __syncthreads();
  const long long NH = NPLL / 2;
  long long idx = (long long)blockIdx.x * 256 + t;
  if (idx >= NH) return;
  float2 a = make_float2(0.f, 0.f);
#pragma unroll 8
  for (int p = 0; p < 40; ++p) {
    float2 v = *(const float2*)&noise[(size_t)p * NPLL + idx * 2];
    a.x += v.x * gg[p];
    a.y += v.y * gg[p];
  }
  *(float2*)&out[idx * 2] = a;
}

extern "C" void kernel_launch(void* const* d_in, const int* in_sizes, int n_in,
                              void* d_out, int out_size, void* d_ws, size_t ws_size,
                              hipStream_t stream) {
  const float* x     = (const float*)d_in[0];
  const float* y     = (const float*)d_in[1];
  const float* W1    = (const float*)d_in[2];
  const float* b1    = (const float*)d_in[3];
  const float* W2    = (const float*)d_in[4];
  const float* b2    = (const float*)d_in[5];
  const float* noise = (const float*)d_in[6];
  float* out  = (float*)d_out;
  float* ws   = (float*)d_ws;   // ~15.7 MB used
  float* base = ws;
  unsigned* ppu = (unsigned*)(ws + WS_PP);
  float* loss = ws + WS_LOSS;
  float* g    = ws + WS_G;
  f16* xf = (f16*)(ws + WS_XF);

  k_xsplit<<<128, 256, 0, stream>>>(x, xf);
  k_base<<<dim3(32, 8), 256, 0, stream>>>(x, W1, b1, base);
  k_big<<<dim3(32, 40), 256, 0, stream>>>(xf, noise, W2, base, ppu);
  k_loss<<<80, 256, 0, stream>>>(ppu, y, b2, noise, loss);
  k_rank<<<1, 128, 0, stream>>>(loss, g);
  k_grad<<<4141, 256, 0, stream>>>(noise, g, out);
}

// Round 12
// 347.180 us; speedup vs baseline: 1.5035x; 1.1914x over previous
//
#include <hip/hip_runtime.h>

// ES gradient for 2-layer MLP (D_IN=1024, HID=2048, D_OUT=10, POP=40, STD=0.1).
// k_xsplit (x -> fragment-order f16 RTN) -> k_base (fp32) ->
// k_big (2-product split MFMA x@E1; double-buffered E LDS; RAW s_barrier +
// counted waits so E/B loads stay in flight ACROSS barriers, 2-step lookahead)
// -> k_loss -> k_rank -> k_grad.
// Rank-exactness verified on HW (R10): absmax 2.441e-4 with 2-product split.
// Register discipline (R5-R10): any __launch_bounds__ min-occupancy arg caps
// VGPR (128 at (256,2)) -> deterministic spills. Leave uncapped (256, no spill).
// Barrier discipline (R11): __syncthreads drains vmcnt(0) -> 1-step lookahead
// max -> ~600cyc exposed HBM latency/step. Raw s_barrier + lgkmcnt(0) keeps
// global loads in flight (T3/T4, learn_hip m201/m218).

#define NPLL 2119690LL          // N_PARAMS
#define S1_  2097152            // W1 end
#define S2_  2099200            // b1 end
#define S3_  2119680            // W2 end

// ws layout (f32 units):
//   base : [0, 524288)            base[j][b]  f32
//   ppu  : [524288, 3801088)      f16-packed [40][2][32 jt][256 b][5 dw]
//   loss : [3801088, 3801168)
//   g    : [3801168, 3801208)
//   xf   : [3801216, +131072)     f16 frag-order [32 kt][16 bblk][4 qh][16 lm][8]
#define WS_PP   524288
#define WS_LOSS 3801088
#define WS_G    3801168
#define WS_XF   3801216

typedef _Float16 f16;
typedef __fp16   fp16x2 __attribute__((ext_vector_type(2)));
typedef _Float16 f16x2t __attribute__((ext_vector_type(2)));
typedef _Float16 f16x8 __attribute__((ext_vector_type(8)));
typedef float    f32x4 __attribute__((ext_vector_type(4)));

__device__ __forceinline__ unsigned pk2r(float a, float b, float& ra, float& rb) {
  fp16x2 h = __builtin_amdgcn_cvt_pkrtz(a, b);   // v_cvt_pkrtz_f16_f32 (RTZ)
  ra = a - (float)h[0];
  rb = b - (float)h[1];
  return __builtin_bit_cast(unsigned, h);
}
__device__ __forceinline__ unsigned pk2(float a, float b) {
  fp16x2 h = __builtin_amdgcn_cvt_pkrtz(a, b);
  return __builtin_bit_cast(unsigned, h);
}
__device__ __forceinline__ unsigned packh(float a, float b) {  // RTN pack
  f16x2t v = {(f16)a, (f16)b};
  return __builtin_bit_cast(unsigned, v);
}
__device__ __forceinline__ float unpk_lo(unsigned u) {
  return (float)__builtin_bit_cast(f16, (unsigned short)(u & 0xffffu));
}
__device__ __forceinline__ float unpk_hi(unsigned u) {
  return (float)__builtin_bit_cast(f16, (unsigned short)(u >> 16));
}

// ---------------- k_xsplit: x -> fragment-order f16 (RTN) -------------------
__global__ __launch_bounds__(256) void k_xsplit(const float* __restrict__ x,
                                                f16* __restrict__ xf) {
  const int idx = blockIdx.x * 256 + threadIdx.x;  // 32768
  const int b  = idx >> 7;           // 0..255
  const int k8 = idx & 127;          // k-octet index
  const int kt = k8 >> 2, qh = k8 & 3;
  const int bblk = b >> 4, lm = b & 15;
  float4 a0 = *(const float4*)&x[(size_t)b * 1024 + k8 * 8];
  float4 a1 = *(const float4*)&x[(size_t)b * 1024 + k8 * 8 + 4];
  uint4 H;
  H.x = packh(a0.x, a0.y);
  H.y = packh(a0.z, a0.w);
  H.z = packh(a1.x, a1.y);
  H.w = packh(a1.z, a1.w);
  f16* dst = &xf[(((size_t)(kt * 16 + bblk) * 4 + qh) * 16 + lm) * 8];
  *(uint4*)dst = H;
}

// ---------------- k_base: base[j][b] = (x @ W1)[b][j] + b1[j] (fp32) --------
__global__ __launch_bounds__(256) void k_base(const float* __restrict__ x,
                                              const float* __restrict__ W1,
                                              const float* __restrict__ b1,
                                              float* __restrict__ base) {
  constexpr int STR = 72;
  __shared__ float xsm[32 * STR];
  __shared__ float es[32 * STR];
  const int t  = threadIdx.x;
  const int j0 = blockIdx.x * 64;
  const int b0 = blockIdx.y * 32;
  const int tj = t & 15;
  const int tb = t >> 4;
  float acc[4][2] = {};
  for (int k0 = 0; k0 < 1024; k0 += 32) {
    __syncthreads();
    {
      int bb = t >> 3, kq = t & 7;
      float4 v = *(const float4*)&x[(size_t)(b0 + bb) * 1024 + k0 + kq * 4];
      int kb = kq * 4;
      xsm[(kb + 0) * STR + bb] = v.x;
      xsm[(kb + 1) * STR + bb] = v.y;
      xsm[(kb + 2) * STR + bb] = v.z;
      xsm[(kb + 3) * STR + bb] = v.w;
    }
#pragma unroll
    for (int r = 0; r < 2; ++r) {
      int idx = t + r * 256;
      int k = idx >> 4, jq = idx & 15, col = jq * 4;
      float4 v = *(const float4*)&W1[(size_t)(k0 + k) * 2048 + j0 + col];
      *(float4*)&es[k * STR + col + 4 * (col >> 5)] = v;
    }
    __syncthreads();
#pragma unroll 8
    for (int k = 0; k < 32; ++k) {
      const int ce = tj * 4;
      float4 e = *(const float4*)&es[k * STR + ce + 4 * (ce >> 5)];
      float2 a = *(const float2*)&xsm[k * STR + tb * 2];
      acc[0][0] += e.x * a.x; acc[0][1] += e.x * a.y;
      acc[1][0] += e.y * a.x; acc[1][1] += e.y * a.y;
      acc[2][0] += e.z * a.x; acc[2][1] += e.z * a.y;
      acc[3][0] += e.w * a.x; acc[3][1] += e.w * a.y;
    }
  }
#pragma unroll
  for (int jj = 0; jj < 4; ++jj) {
    int j = j0 + tj * 4 + jj;
    float bv = b1[j];
    float2 o = make_float2(acc[jj][0] + bv, acc[jj][1] + bv);
    *(float2*)&base[(size_t)j * 256 + b0 + tb * 2] = o;
  }
}

// ---------------- k_big: 2-product split MFMA x@E1 + fused epilogue ---------
// grid (32 jt, 40 p), 256 threads = 4 waves; block tile j64 x b256; each wave
// owns a 64-wide b-slice and all 64 j rows. eA double-buffered (2 x 8 KB).
// Per step: cvt cur->LDS | issue loads(ks+2) | lgkmcnt(0) | RAW barrier |
// fence | ds_read + MFMA. vmcnt never drained in-loop (counted waits only).
__global__ __launch_bounds__(256) void k_big(const f16* __restrict__ xf,
                                             const float* __restrict__ noise,
                                             const float* __restrict__ W2,
                                             const float* __restrict__ base,
                                             unsigned* __restrict__ ppu) {
  __shared__ __align__(16) char smem[16384];   // eA[0] | eA[1]
  float* w2l = (float*)smem;       // epilogue overlay of buffer 0 (5.4 KB)
  float* e2l = w2l + 640;
  float* e1l = e2l + 640;

  const int t    = threadIdx.x;
  const int jt   = blockIdx.x, p = blockIdx.y;
  const int j0   = jt * 64;
  const int wave = t >> 6, lane = t & 63;
  const int lm   = lane & 15, qh = lane >> 4;   // frag row / k-octet
  const int g4   = qh * 4;
  const int bw   = wave * 64;
  const size_t pN = (size_t)p * NPLL;
  const int srow = t & 63, sq = t >> 6;         // staging role
  const int sswz = (srow & 7) << 3;
  const int aswz = (lm & 7) << 3;

  f16* eA0 = (f16*)smem;
  f16* eA1 = (f16*)(smem + 8192);

  float veA[8], veB[8];
  f16x8 Ba[4], Bb[4];
  f32x4 acc[4][4];
#pragma unroll
  for (int a = 0; a < 4; ++a)
#pragma unroll
    for (int b = 0; b < 4; ++b) acc[a][b] = (f32x4){0.f, 0.f, 0.f, 0.f};

  const float* Ebase = noise + pN + (size_t)(sq * 8) * 2048 + j0 + srow;
  const int boff = (wave * 4) * 512 + qh * 128 + lm * 8;

  // prologue: loads for ks = 0 (veA/Ba) and ks = 1 (veB/Bb)
#pragma unroll
  for (int d = 0; d < 8; ++d) veA[d] = Ebase[(size_t)d * 2048];
#pragma unroll
  for (int nf = 0; nf < 4; ++nf)
    Ba[nf] = *(const f16x8*)&xf[boff + nf * 512];
#pragma unroll
  for (int d = 0; d < 8; ++d) veB[d] = Ebase[65536 + (size_t)d * 2048];
#pragma unroll
  for (int nf = 0; nf < 4; ++nf)
    Bb[nf] = *(const f16x8*)&xf[8192 + boff + nf * 512];

#define KSTEP(EAC, VE, BF, KS)                                                 \
  do {                                                                         \
    { /* cvt VE -> EAC (compiler waits counted vmcnt for VE only) */           \
      float r0, r1, r2, r3, r4, r5, r6, r7;                                    \
      uint4 H, L;                                                              \
      H.x = pk2r(VE[0], VE[1], r0, r1);                                        \
      H.y = pk2r(VE[2], VE[3], r2, r3);                                        \
      H.z = pk2r(VE[4], VE[5], r4, r5);                                        \
      H.w = pk2r(VE[6], VE[7], r6, r7);                                        \
      *(uint4*)&EAC[srow * 64 + ((sq * 8) ^ sswz)] = H;                        \
      L.x = pk2(r0, r1); L.y = pk2(r2, r3);                                    \
      L.z = pk2(r4, r5); L.w = pk2(r6, r7);                                    \
      *(uint4*)&EAC[srow * 64 + (((sq + 4) * 8) ^ sswz)] = L;                  \
    }                                                                          \
    if ((KS) + 2 < 32) { /* issue E(KS+2) into VE: ~2 steps in flight */       \
      const float* En = Ebase + (size_t)((KS) + 2) * 65536;                    \
      _Pragma("unroll") for (int d = 0; d < 8; ++d)                            \
        VE[d] = En[(size_t)d * 2048];                                          \
    }                                                                          \
    asm volatile("s_waitcnt lgkmcnt(0)" ::: "memory");  /* ds_writes done */   \
    __builtin_amdgcn_s_barrier();                       /* raw: no vm drain */ \
    asm volatile("" ::: "memory");                      /* no hoist above */   \
    _Pragma("unroll") for (int mf = 0; mf < 4; ++mf) {                         \
      const int ra = mf * 16 + lm;                                             \
      f16x8 Ah = *(const f16x8*)&EAC[ra * 64 + ((qh * 8) ^ aswz)];             \
      f16x8 Al = *(const f16x8*)&EAC[ra * 64 + (((qh + 4) * 8) ^ aswz)];       \
      _Pragma("unroll") for (int nf = 0; nf < 4; ++nf) {                       \
        acc[mf][nf] = __builtin_amdgcn_mfma_f32_16x16x32_f16(Ah, BF[nf], acc[mf][nf], 0, 0, 0); \
        acc[mf][nf] = __builtin_amdgcn_mfma_f32_16x16x32_f16(Al, BF[nf], acc[mf][nf], 0, 0, 0); \
      }                                                                        \
    }                                                                          \
    if ((KS) + 2 < 32) { /* issue B(KS+2) into BF (WAR after last MFMA) */     \
      const f16* xn = xf + (size_t)((KS) + 2) * 8192;                          \
      _Pragma("unroll") for (int nf = 0; nf < 4; ++nf)                         \
        BF[nf] = *(const f16x8*)&xn[boff + nf * 512];                          \
    }                                                                          \
  } while (0)

  for (int ks = 0; ks < 32; ks += 2) {
    KSTEP(eA0, veA, Ba, ks);
    KSTEP(eA1, veB, Bb, ks + 1);
  }
#undef KSTEP

  // ---- epilogue: tables overlay dead eA buffer 0 ----
  __syncthreads();
  for (int i = t; i < 640; i += 256) {
    w2l[i] = W2[j0 * 10 + i];
    e2l[i] = noise[pN + S2_ + (size_t)j0 * 10 + i];
  }
  if (t < 64) e1l[t] = noise[pN + S1_ + j0 + t];
  __syncthreads();

#pragma unroll 1
  for (int s = 0; s < 2; ++s) {
    const float sf = s ? -0.1f : 0.1f;
    float ppv[4][10];
#pragma unroll
    for (int nf = 0; nf < 4; ++nf)
#pragma unroll
      for (int o = 0; o < 10; ++o) ppv[nf][o] = 0.f;
#pragma unroll
    for (int mf = 0; mf < 4; ++mf)
#pragma unroll
      for (int r = 0; r < 4; ++r) {
        const int jl = mf * 16 + g4 + r;       // D row = (lane>>4)*4 + reg
        const float e1v = e1l[jl];
        float w2s[10];
#pragma unroll
        for (int o = 0; o < 10; ++o)
          w2s[o] = fmaf(sf, e2l[jl * 10 + o], w2l[jl * 10 + o]);
#pragma unroll
        for (int nf = 0; nf < 4; ++nf) {
          const float bs = base[(size_t)(j0 + jl) * 256 + bw + nf * 16 + lm];
          const float h = fmaxf(fmaf(sf, acc[mf][nf][r] + e1v, bs), 0.f);
#pragma unroll
          for (int o = 0; o < 10; ++o) ppv[nf][o] = fmaf(h, w2s[o], ppv[nf][o]);
        }
      }
    // sum the 4 row-groups (lane bits 4,5); wave covers all 64 j
#pragma unroll
    for (int nf = 0; nf < 4; ++nf)
#pragma unroll
      for (int o = 0; o < 10; ++o) {
        float v = ppv[nf][o];
        v += __shfl_xor(v, 16, 64);
        v += __shfl_xor(v, 32, 64);
        ppv[nf][o] = v;
      }
    if (lane < 16) {
#pragma unroll
      for (int nf = 0; nf < 4; ++nf) {
        const int bl = bw + nf * 16 + lm;
        const size_t u0 = ((((size_t)p * 2 + s) * 32 + jt) * 256 + bl) * 5;
        ppu[u0 + 0] = packh(ppv[nf][0], ppv[nf][1]);
        ppu[u0 + 1] = packh(ppv[nf][2], ppv[nf][3]);
        ppu[u0 + 2] = packh(ppv[nf][4], ppv[nf][5]);
        ppu[u0 + 3] = packh(ppv[nf][6], ppv[nf][7]);
        ppu[u0 + 4] = packh(ppv[nf][8], ppv[nf][9]);
      }
    }
  }
}

// ---------------- k_loss: 80 losses ----------------
__global__ __launch_bounds__(256) void k_loss(const unsigned* __restrict__ ppu,
                                              const float* __restrict__ y,
                                              const float* __restrict__ b2,
                                              const float* __restrict__ noise,
                                              float* __restrict__ loss) {
  const int b = threadIdx.x;
  const int p = blockIdx.x >> 1, s = blockIdx.x & 1;
  const float sf = s ? -0.1f : 0.1f;
  const size_t pN = (size_t)p * NPLL;
  float pred[10];
#pragma unroll
  for (int o = 0; o < 10; ++o) pred[o] = b2[o] + sf * noise[pN + S3_ + o];
  for (int jt = 0; jt < 32; ++jt) {
    const size_t u0 = ((((size_t)p * 2 + s) * 32 + jt) * 256 + b) * 5;
#pragma unroll
    for (int q = 0; q < 5; ++q) {
      unsigned u = ppu[u0 + q];
      pred[2 * q]     += unpk_lo(u);
      pred[2 * q + 1] += unpk_hi(u);
    }
  }
  float e = 0.f;
#pragma unroll
  for (int o = 0; o < 10; ++o) {
    float d = pred[o] - y[b * 10 + o];
    e += d * d;
  }
  __shared__ float red[256];
  red[b] = e;
  __syncthreads();
  for (int st = 128; st > 0; st >>= 1) {
    if (b < st) red[b] += red[b + st];
    __syncthreads();
  }
  if (b == 0) loss[blockIdx.x] = red[0] * (1.0f / 2560.0f);
}

// ---------------- k_rank: stable centered ranks -> pair coefficients --------
__global__ void k_rank(const float* __restrict__ loss, float* __restrict__ g) {
  __shared__ float ls[80];
  __shared__ float rk[80];
  const int t = threadIdx.x;
  if (t < 80) ls[t] = loss[t];
  __syncthreads();
  if (t < 80) {
    float li = ls[t];
    int r = 0;
    for (int j = 0; j < 80; ++j) {
      float lj = ls[j];
      r += (lj < li) || (lj == li && j < t);  // stable tie-break = argsort
    }
    rk[t] = (float)r;
  }
  __syncthreads();
  if (t < 40) g[t] = (rk[2 * t] - rk[2 * t + 1]) * (1.0f / (79.0f * 40.0f));
}

// ---------------- k_grad: out[k] = sum_p noise[p][k] * g[p] -----------------
__global__ __launch_bounds__(256) void k_grad(const float* __restrict__ noise,
                                              const float* __restrict__ g,
                                              float* __restrict__ out) {
  __shared__ float gg[40];
  const int t = threadIdx.x;
  if (t < 40) gg[t] = g[t];
  __syncthreads();
  const long long NH = NPLL / 2;
  long long idx = (long long)blockIdx.x * 256 + t;
  if (idx >= NH) return;
  float2 a = make_float2(0.f, 0.f);
#pragma unroll 8
  for (int p = 0; p < 40; ++p) {
    float2 v = *(const float2*)&noise[(size_t)p * NPLL + idx * 2];
    a.x += v.x * gg[p];
    a.y += v.y * gg[p];
  }
  *(float2*)&out[idx * 2] = a;
}

extern "C" void kernel_launch(void* const* d_in, const int* in_sizes, int n_in,
                              void* d_out, int out_size, void* d_ws, size_t ws_size,
                              hipStream_t stream) {
  const float* x     = (const float*)d_in[0];
  const float* y     = (const float*)d_in[1];
  const float* W1    = (const float*)d_in[2];
  const float* b1    = (const float*)d_in[3];
  const float* W2    = (const float*)d_in[4];
  const float* b2    = (const float*)d_in[5];
  const float* noise = (const float*)d_in[6];
  float* out  = (float*)d_out;
  float* ws   = (float*)d_ws;   // ~15.7 MB used
  float* base = ws;
  unsigned* ppu = (unsigned*)(ws + WS_PP);
  float* loss = ws + WS_LOSS;
  float* g    = ws + WS_G;
  f16* xf = (f16*)(ws + WS_XF);

  k_xsplit<<<128, 256, 0, stream>>>(x, xf);
  k_base<<<dim3(32, 8), 256, 0, stream>>>(x, W1, b1, base);
  k_big<<<dim3(32, 40), 256, 0, stream>>>(xf, noise, W2, base, ppu);
  k_loss<<<80, 256, 0, stream>>>(ppu, y, b2, noise, loss);
  k_rank<<<1, 128, 0, stream>>>(loss, g);
  k_grad<<<4141, 256, 0, stream>>>(noise, g, out);
}